// Round 2
// baseline (905.473 us; speedup 1.0000x reference)
//
#include <hip/hip_runtime.h>
#include <hip/hip_bf16.h>
#include <math.h>

#define BATCH 4
#define SEQ   4096
#define EMB   1024
#define HD    64
#define KST   65    // LDS stride pad: bank (j*65+d)%32=(j+d)%32 -> 2-way = free
#define RPB   8     // rows per block in projection

static __device__ __forceinline__ float bf2f(unsigned int u16) {
    union { unsigned int i; float f; } v;
    v.i = u16 << 16;
    return v.f;
}

// --------- dtype detector: bf16 N(0,1) never has exponent>146; fp32 read as
// --------- bf16 halfwords does (~42% of low halves). Deterministic per input.
__global__ void detect_dtype(const unsigned short* __restrict__ x,
                             int* __restrict__ flag)
{
    const int tid = threadIdx.x;
    int big = 0;
    for (int i = tid; i < 2048; i += 64) {
        const int e = (x[i] >> 7) & 0xff;
        if (e > 146) big++;                 // |bf16| > ~1e6 (incl inf/nan)
    }
    #pragma unroll
    for (int off = 32; off; off >>= 1) big += __shfl_xor(big, off);
    if (tid == 0) *flag = (big > 200) ? 0 : 1;   // 0 = fp32 inputs, 1 = bf16
}

// ---------------- QKV projection: [B*S,1024] x [1024,64] x3 -> fp32 ws ----
__global__ __launch_bounds__(192) void qkv_proj(
    const void* __restrict__ xp,
    const void* __restrict__ Wqp, const void* __restrict__ Wkp,
    const void* __restrict__ Wvp, const int* __restrict__ flagp,
    float* __restrict__ Q, float* __restrict__ K, float* __restrict__ V)
{
    __shared__ float xs[RPB * EMB];        // 32 KB
    const int tid = threadIdx.x;
    const size_t row0 = (size_t)blockIdx.x * RPB;
    const int isbf = *flagp;

    if (isbf) {
        const unsigned int* xu =
            (const unsigned int*)((const unsigned short*)xp + row0 * EMB);
        for (int i = tid; i < RPB * EMB / 2; i += 192) {
            const unsigned int u = xu[i];
            xs[2 * i]     = bf2f(u & 0xffffu);
            xs[2 * i + 1] = bf2f(u >> 16);
        }
    } else {
        const float4* xf = (const float4*)((const float*)xp + row0 * EMB);
        for (int i = tid; i < RPB * EMB / 4; i += 192) {
            const float4 v = xf[i];
            xs[4 * i]     = v.x; xs[4 * i + 1] = v.y;
            xs[4 * i + 2] = v.z; xs[4 * i + 3] = v.w;
        }
    }
    __syncthreads();

    const int m = tid / 64, d = tid & 63;  // wave m owns matrix m, lane = out dim
    const void* Wp = (m == 0) ? Wqp : (m == 1 ? Wkp : Wvp);

    float acc[RPB];
    #pragma unroll
    for (int r = 0; r < RPB; ++r) acc[r] = 0.f;

    if (isbf) {
        const unsigned short* W = (const unsigned short*)Wp;
        for (int e = 0; e < EMB; e += 4) {
            const float w0 = bf2f(W[(e + 0) * HD + d]);
            const float w1 = bf2f(W[(e + 1) * HD + d]);
            const float w2 = bf2f(W[(e + 2) * HD + d]);
            const float w3 = bf2f(W[(e + 3) * HD + d]);
            #pragma unroll
            for (int r = 0; r < RPB; ++r) {
                const float4 xv = *(const float4*)&xs[r * EMB + e];
                acc[r] += xv.x * w0 + xv.y * w1 + xv.z * w2 + xv.w * w3;
            }
        }
    } else {
        const float* W = (const float*)Wp;
        for (int e = 0; e < EMB; e += 4) {
            const float w0 = W[(e + 0) * HD + d];
            const float w1 = W[(e + 1) * HD + d];
            const float w2 = W[(e + 2) * HD + d];
            const float w3 = W[(e + 3) * HD + d];
            #pragma unroll
            for (int r = 0; r < RPB; ++r) {
                const float4 xv = *(const float4*)&xs[r * EMB + e];
                acc[r] += xv.x * w0 + xv.y * w1 + xv.z * w2 + xv.w * w3;
            }
        }
    }

    float* Out = (m == 0) ? Q : (m == 1 ? K : V);
    #pragma unroll
    for (int r = 0; r < RPB; ++r)
        Out[(row0 + r) * HD + d] = acc[r];
}

// ---------------- causal flash attention, 4 query rows / block ------------
__global__ __launch_bounds__(256) void attn_fwd(
    const float* __restrict__ Q, const float* __restrict__ K,
    const float* __restrict__ V, const int* __restrict__ flagp,
    void* __restrict__ outp)
{
    __shared__ float Kt[64 * KST];   // 16.25 KB
    __shared__ float Vt[64 * KST];
    __shared__ float q_s[4][64];
    __shared__ float p_s[4][64];

    const int b    = blockIdx.y;
    const int i0   = blockIdx.x * 4;
    const int w    = threadIdx.x >> 6;     // wave id = row offset within block
    const int lane = threadIdx.x & 63;
    const int row  = i0 + w;
    const int isbf = *flagp;

    const float* Qb = Q + (size_t)b * SEQ * HD;
    const float* Kb = K + (size_t)b * SEQ * HD;
    const float* Vb = V + (size_t)b * SEQ * HD;

    q_s[w][lane] = Qb[(size_t)row * HD + lane];  // visible after first barrier

    float m = -INFINITY, l = 0.f, o = 0.f;       // o: lane holds dim `lane`
    const int nt = i0 / 64 + 1;                  // uniform across the 4 rows

    for (int t = 0; t < nt; ++t) {
        const int k0 = t * 64;
        __syncthreads();                         // protect previous tile reads
        for (int it = threadIdx.x; it < 64 * 16; it += 256) {
            const int j = it >> 4;
            const int c = (it & 15) << 2;
            const float4 kv = *(const float4*)(Kb + (size_t)(k0 + j) * HD + c);
            const float4 vv = *(const float4*)(Vb + (size_t)(k0 + j) * HD + c);
            float* kd = &Kt[j * KST + c];
            kd[0] = kv.x; kd[1] = kv.y; kd[2] = kv.z; kd[3] = kv.w;
            float* vd = &Vt[j * KST + c];
            vd[0] = vv.x; vd[1] = vv.y; vd[2] = vv.z; vd[3] = vv.w;
        }
        __syncthreads();

        // scores: lane j handles key k0+j
        float s = 0.f;
        const float* krow = &Kt[lane * KST];
        const float* qrow = q_s[w];
        #pragma unroll
        for (int dd = 0; dd < 64; dd += 4) {
            const float4 qv = *(const float4*)&qrow[dd];   // same-addr broadcast
            s += qv.x * krow[dd] + qv.y * krow[dd + 1]
               + qv.z * krow[dd + 2] + qv.w * krow[dd + 3];
        }
        s *= 0.125f;                                       // 1/sqrt(64)
        if (k0 + lane > row) s = -INFINITY;                // causal mask

        // online softmax
        float mt = s;
        #pragma unroll
        for (int off = 32; off > 0; off >>= 1) mt = fmaxf(mt, __shfl_xor(mt, off));
        const float mn    = fmaxf(m, mt);                  // finite: key k0<=row
        const float alpha = __expf(m - mn);                // first tile: exp(-inf)=0
        const float p     = __expf(s - mn);                // masked lanes -> 0
        float ps = p;
        #pragma unroll
        for (int off = 32; off > 0; off >>= 1) ps += __shfl_xor(ps, off);
        l = l * alpha + ps;
        m = mn;

        // broadcast p across the wave via LDS (same-wave RAW: in-order DS pipe)
        p_s[w][lane] = p;
        __threadfence_block();

        // PV: lane d accumulates sum_j p_j * V[j][d]
        float pv = 0.f;
        const float* prow = p_s[w];
        #pragma unroll
        for (int j = 0; j < 64; j += 4) {
            const float4 pj = *(const float4*)&prow[j];    // broadcast
            pv += pj.x * Vt[(j + 0) * KST + lane] + pj.y * Vt[(j + 1) * KST + lane]
                + pj.z * Vt[(j + 2) * KST + lane] + pj.w * Vt[(j + 3) * KST + lane];
        }
        o = o * alpha + pv;
    }

    const float res = o / l;
    const size_t oidx = ((size_t)b * SEQ + row) * HD + lane;
    if (isbf) ((__hip_bfloat16*)outp)[oidx] = __float2bfloat16(res);
    else      ((float*)outp)[oidx] = res;
}

extern "C" void kernel_launch(void* const* d_in, const int* in_sizes, int n_in,
                              void* d_out, int out_size, void* d_ws, size_t ws_size,
                              hipStream_t stream)
{
    const void* x  = d_in[0];
    const void* Wq = d_in[1];
    const void* Wk = d_in[2];
    const void* Wv = d_in[3];

    int*   flag = (int*)d_ws;
    float* Q    = (float*)((char*)d_ws + 256);      // 3 x 4 MB fp32 scratch
    float* K    = Q + (size_t)BATCH * SEQ * HD;
    float* V    = K + (size_t)BATCH * SEQ * HD;

    detect_dtype<<<1, 64, 0, stream>>>((const unsigned short*)x, flag);

    qkv_proj<<<BATCH * SEQ / RPB, 192, 0, stream>>>(x, Wq, Wk, Wv, flag, Q, K, V);

    dim3 grid(SEQ / 4, BATCH);
    attn_fwd<<<grid, 256, 0, stream>>>(Q, K, V, flag, d_out);
}